// Round 9
// baseline (169.210 us; speedup 1.0000x reference)
//
#include <hip/hip_runtime.h>

// StructuralLoss: windowed ZNCC, sigma=4 -> w=2 (4x4 box windows).
//
// Structure: wave-local shuffle halo exchange (R7), zero barriers; lane owns
// 2 cols; raw-row ring in registers; H ring 4-deep; rsq epilogue; EDGEY
// specialization; block atomic.
//
// R8 post-mortem: 56us, VALU 39%, VGPR 60, single-round grid OK. Real VALU
// work ~22us -> still ~60% idle. Cause: 1-step prefetch distance (~800 wall
// cyc cover) vs ~900cy HBM latency, and symmetric waves stall TOGETHER.
//
// R9: 5-slot ring -> 2-step prefetch distance. At step rr (c-row r), slots
// hold rows r-1..r+2 live + r+3 arriving; after vs consumes row r-1 its slot
// is exactly where row r+4 lands (slot(u) = (u-y0+2) mod 5). Issue-to-wait
// distance doubles to ~1900 wall cyc >> 900. Cost +4 VGPR (ring 20) -> ~64
// total = the 4-waves/SIMD edge. Robustness: plain launch_bounds (R1/R3
// lesson: never pin below natural need) + grid (9,84) = 756 blocks, which
// is single-round BOTH at 4/SIMD (<=1024) and 3/SIMD (<=768) -- no
// quantization cliff either way. Phase period lcm(4,5)=20: 52 steps =
// 2x20 + 12-tail (40 = 0 mod 20 keeps ring/H phases aligned).

#define HH 4096
#define WW 4096
constexpr int RY   = 49;             // output rows per tile (49*84 = 4116 >= 4096)
constexpr int NYB  = 84;             // y tiles
constexpr int WOWN = 120;            // owned cols per wave
constexpr int WPB  = 4;              // waves per block
constexpr int NXB  = 9;              // x blocks (9*4*120 = 4320 >= 4096)
constexpr float EPf = 1e-20f;

__device__ __forceinline__ float up1(float v) { return __shfl_up(v, 1, 64); }
__device__ __forceinline__ float dn1(float v) { return __shfl_down(v, 1, 64); }

struct Regs {
    float ra[5][2], rb[5][2];               // raw ring: 5 rows x 2 cols x 2 imgs
    float Hii[4][2], Hjj[4][2], Hij[4][2];  // H ring per c-row
    float mc;                               // col-pair validity (image pad)
    float ownf;                             // ownership mask for emit
    float acc;
};

template <int SLOT, bool EDGEY>
__device__ __forceinline__ void ld_row(Regs& R,
        const float* __restrict__ i1, const float* __restrict__ i2,
        int t, int p0) {
    bool ok = ((unsigned)p0 < (unsigned)WW);
    if (EDGEY) ok = ok && ((unsigned)t < (unsigned)HH);
    float2 va = make_float2(0.f, 0.f), vb = make_float2(0.f, 0.f);
    if (ok) {
        const size_t off = (size_t)t * WW + (unsigned)p0;
        va = *(const float2*)(i1 + off);
        vb = *(const float2*)(i2 + off);
    }
    R.ra[SLOT][0] = va.x; R.ra[SLOT][1] = va.y;
    R.rb[SLOT][0] = vb.x; R.rb[SLOT][1] = vb.y;
}

// Step rr (c-row r = y0-1+rr), KK = rr % 20. Row u lives in slot (u-y0+2)%5.
template <int KK, bool EDGEY, bool DOLOAD>
__device__ __forceinline__ void step(Regs& R, int rr, int y0, int p0,
        const float* __restrict__ i1, const float* __restrict__ i2) {
    constexpr int Sm1 = (KK + 0) % 5;   // row r-1 (consumed by vs; then load target r+4)
    constexpr int S0  = (KK + 1) % 5;   // row r (center)
    constexpr int Sp1 = (KK + 2) % 5;   // row r+1
    constexpr int Sp2 = (KK + 3) % 5;   // row r+2
    // slot (KK+4)%5 holds row r+3, arriving (issued 1 step ago, used next step)
    constexpr int HS  = KK % 4;         // H ring slot for c-row r
    const int r = y0 - 1 + rr;

    // vertical 4-sums at own 2 cols (consumes oldest slot Sm1)
    const float vs1_0 = (R.ra[Sm1][0] + R.ra[S0][0]) + (R.ra[Sp1][0] + R.ra[Sp2][0]);
    const float vs1_1 = (R.ra[Sm1][1] + R.ra[S0][1]) + (R.ra[Sp1][1] + R.ra[Sp2][1]);
    const float vs2_0 = (R.rb[Sm1][0] + R.rb[S0][0]) + (R.rb[Sp1][0] + R.rb[Sp2][0]);
    const float vs2_1 = (R.rb[Sm1][1] + R.rb[S0][1]) + (R.rb[Sp1][1] + R.rb[Sp2][1]);

    // halo shuffles round 1: vs at cols p0-1 (left lane) and p0+2,p0+3 (right)
    const float vL1  = up1(vs1_1), vL2  = up1(vs2_1);
    const float vR10 = dn1(vs1_0), vR11 = dn1(vs1_1);
    const float vR20 = dn1(vs2_0), vR21 = dn1(vs2_1);

    // issue loads for row r+4 into the just-freed slot; consumed at step rr+2
    if (DOLOAD)
        ld_row<Sm1, EDGEY>(R, i1, i2, y0 + 3 + rr, p0);

    // mu over cols [c-1, c+2]
    const float mu1_0 = ((vL1 + vs1_0) + (vs1_1 + vR10)) * 0.0625f;
    const float mu1_1 = ((vs1_0 + vs1_1) + (vR10 + vR11)) * 0.0625f;
    const float mu2_0 = ((vL2 + vs2_0) + (vs2_1 + vR20)) * 0.0625f;
    const float mu2_1 = ((vs2_0 + vs2_1) + (vR20 + vR21)) * 0.0625f;

    float msk = R.mc;
    if (EDGEY) msk *= (((unsigned)r < (unsigned)HH) ? 1.f : 0.f);

    const float c1_0 = (R.ra[S0][0] - mu1_0) * msk;
    const float c1_1 = (R.ra[S0][1] - mu1_1) * msk;
    const float c2_0 = (R.rb[S0][0] - mu2_0) * msk;
    const float c2_1 = (R.rb[S0][1] - mu2_1) * msk;

    // halo shuffles round 2: centered values at cols p0-1, p0+2, p0+3
    const float cL1  = up1(c1_1), cL2  = up1(c2_1);
    const float cR10 = dn1(c1_0), cR11 = dn1(c1_1);
    const float cR20 = dn1(c2_0), cR21 = dn1(c2_1);

    // products (own + halo, computed locally)
    const float pii0 = c1_0 * c1_0, pjj0 = c2_0 * c2_0, pij0 = c1_0 * c2_0;
    const float pii1 = c1_1 * c1_1, pjj1 = c2_1 * c2_1, pij1 = c1_1 * c2_1;
    const float pLii = cL1 * cL1,  pLjj = cL2 * cL2,  pLij = cL1 * cL2;
    const float pR0ii = cR10 * cR10, pR0jj = cR20 * cR20, pR0ij = cR10 * cR20;
    const float pR1ii = cR11 * cR11, pR1jj = cR21 * cR21, pR1ij = cR11 * cR21;

    // horizontal 4-sums over cols [o-1, o+2] -> H ring slot HS
    {
        const float s = pii0 + pii1;
        R.Hii[HS][0] = (pLii + s) + pR0ii;
        R.Hii[HS][1] = (s + pR0ii) + pR1ii;
    }
    {
        const float s = pjj0 + pjj1;
        R.Hjj[HS][0] = (pLjj + s) + pR0jj;
        R.Hjj[HS][1] = (s + pR0jj) + pR1jj;
    }
    {
        const float s = pij0 + pij1;
        R.Hij[HS][0] = (pLij + s) + pR0ij;
        R.Hij[HS][1] = (s + pR0ij) + pR1ij;
    }

    // emit output row i = r-2 once H ring holds c-rows i-1..i+2.
    // EDGEY bottom-overhang tiles: skip rows i >= HH (wave-uniform guard).
    if (rr >= 3 && (!EDGEY || (r - 2 < HH))) {
#pragma unroll
        for (int q = 0; q < 2; ++q) {
            float sii = (R.Hii[0][q] + R.Hii[1][q]) + (R.Hii[2][q] + R.Hii[3][q]);
            float sjj = (R.Hjj[0][q] + R.Hjj[1][q]) + (R.Hjj[2][q] + R.Hjj[3][q]);
            float sij = (R.Hij[0][q] + R.Hij[1][q]) + (R.Hij[2][q] + R.Hij[3][q]);
            sii = fmaxf(sii, EPf);
            sjj = fmaxf(sjj, EPf);
            const float pr = fmaxf(sii * sjj, 1e-35f);  // denormal-flush guard
            float L = sij * __builtin_amdgcn_rsqf(pr);
            L = fmaxf(L, -1.f);
            R.acc += R.ownf * (1.f - L);
        }
    }
}

template <bool EDGEY>
__device__ float run_tile(const float* __restrict__ i1, const float* __restrict__ i2,
                          int y0, int p0, float mc, float ownf) {
    Regs R;
    R.mc = mc; R.ownf = ownf; R.acc = 0.f;

    // prime ring: rows y0-2..y0+2 -> slots 0..4  (slot = (row-y0+2)%5)
    ld_row<0, EDGEY>(R, i1, i2, y0 - 2, p0);
    ld_row<1, EDGEY>(R, i1, i2, y0 - 1, p0);
    ld_row<2, EDGEY>(R, i1, i2, y0,     p0);
    ld_row<3, EDGEY>(R, i1, i2, y0 + 1, p0);
    ld_row<4, EDGEY>(R, i1, i2, y0 + 2, p0);

    // steps rr = 0..RY+2 = 0..51 (52 = 2x20 + 12). Step rr issues row
    // y0+3+rr; last row needed y0+RY+3 -> last load at rr = RY = 49.
#pragma unroll 1
    for (int g = 0; g < 2; ++g) {
        const int rb = g * 20;
        step< 0, EDGEY, true>(R, rb +  0, y0, p0, i1, i2);
        step< 1, EDGEY, true>(R, rb +  1, y0, p0, i1, i2);
        step< 2, EDGEY, true>(R, rb +  2, y0, p0, i1, i2);
        step< 3, EDGEY, true>(R, rb +  3, y0, p0, i1, i2);
        step< 4, EDGEY, true>(R, rb +  4, y0, p0, i1, i2);
        step< 5, EDGEY, true>(R, rb +  5, y0, p0, i1, i2);
        step< 6, EDGEY, true>(R, rb +  6, y0, p0, i1, i2);
        step< 7, EDGEY, true>(R, rb +  7, y0, p0, i1, i2);
        step< 8, EDGEY, true>(R, rb +  8, y0, p0, i1, i2);
        step< 9, EDGEY, true>(R, rb +  9, y0, p0, i1, i2);
        step<10, EDGEY, true>(R, rb + 10, y0, p0, i1, i2);
        step<11, EDGEY, true>(R, rb + 11, y0, p0, i1, i2);
        step<12, EDGEY, true>(R, rb + 12, y0, p0, i1, i2);
        step<13, EDGEY, true>(R, rb + 13, y0, p0, i1, i2);
        step<14, EDGEY, true>(R, rb + 14, y0, p0, i1, i2);
        step<15, EDGEY, true>(R, rb + 15, y0, p0, i1, i2);
        step<16, EDGEY, true>(R, rb + 16, y0, p0, i1, i2);
        step<17, EDGEY, true>(R, rb + 17, y0, p0, i1, i2);
        step<18, EDGEY, true>(R, rb + 18, y0, p0, i1, i2);
        step<19, EDGEY, true>(R, rb + 19, y0, p0, i1, i2);
    }
    // tail rr = 40..51 (KK = 0..11; 40 = 0 mod 20 keeps phases aligned)
    step< 0, EDGEY, true >(R, 40, y0, p0, i1, i2);
    step< 1, EDGEY, true >(R, 41, y0, p0, i1, i2);
    step< 2, EDGEY, true >(R, 42, y0, p0, i1, i2);
    step< 3, EDGEY, true >(R, 43, y0, p0, i1, i2);
    step< 4, EDGEY, true >(R, 44, y0, p0, i1, i2);
    step< 5, EDGEY, true >(R, 45, y0, p0, i1, i2);
    step< 6, EDGEY, true >(R, 46, y0, p0, i1, i2);
    step< 7, EDGEY, true >(R, 47, y0, p0, i1, i2);
    step< 8, EDGEY, true >(R, 48, y0, p0, i1, i2);
    step< 9, EDGEY, true >(R, 49, y0, p0, i1, i2);
    step<10, EDGEY, false>(R, 50, y0, p0, i1, i2);
    step<11, EDGEY, false>(R, 51, y0, p0, i1, i2);

    return R.acc;
}

__global__ __launch_bounds__(256) void xcorr_loss_kernel(
        const float* __restrict__ img1, const float* __restrict__ img2,
        double* __restrict__ ws) {
    const int tid  = threadIdx.x;
    const int lane = tid & 63;
    const int wv   = tid >> 6;
    const int WX0  = (blockIdx.x * WPB + wv) * WOWN;
    const int p0   = WX0 - 4 + 2 * lane;        // own cols p0, p0+1 (p0 even)
    const int y0   = blockIdx.y * RY;

    const float mc   = ((unsigned)p0 < (unsigned)WW) ? 1.f : 0.f;
    const float ownf = (lane >= 2 && lane <= 61 && (unsigned)p0 < (unsigned)WW)
                       ? 1.f : 0.f;

    float acc;
    if (blockIdx.y == 0 || blockIdx.y == gridDim.y - 1)
        acc = run_tile<true >(img1, img2, y0, p0, mc, ownf);
    else
        acc = run_tile<false>(img1, img2, y0, p0, mc, ownf);

    // wave reduction -> LDS -> one double atomic per block
    float wsum = acc;
#pragma unroll
    for (int off = 32; off > 0; off >>= 1)
        wsum += __shfl_down(wsum, off, 64);

    __shared__ float wpart[WPB];
    if (lane == 0) wpart[wv] = wsum;
    __syncthreads();
    if (tid == 0)
        atomicAdd(ws, (double)((wpart[0] + wpart[1]) + (wpart[2] + wpart[3])));
}

__global__ void finalize_kernel(const double* __restrict__ ws, float* __restrict__ out) {
    double mean = ws[0] / ((double)HH * (double)WW);
    out[0] = (float)mean;
    out[1] = (float)mean;
}

extern "C" void kernel_launch(void* const* d_in, const int* in_sizes, int n_in,
                              void* d_out, int out_size, void* d_ws, size_t ws_size,
                              hipStream_t stream) {
    const float* img1 = (const float*)d_in[0];  // outputs
    const float* img2 = (const float*)d_in[1];  // labels
    double* ws = (double*)d_ws;

    hipMemsetAsync(d_ws, 0, sizeof(double), stream);

    dim3 grid(NXB, NYB);   // (9, 84) = 756 blocks: single-round at 3 OR 4 w/SIMD
    xcorr_loss_kernel<<<grid, dim3(256), 0, stream>>>(img1, img2, ws);
    finalize_kernel<<<1, 1, 0, stream>>>(ws, (float*)d_out);
}

// Round 10
// 159.353 us; speedup vs baseline: 1.0619x; 1.0619x over previous
//
#include <hip/hip_runtime.h>

// StructuralLoss: windowed ZNCC, sigma=4 -> w=2 (4x4 box windows).
//
// Structure: wave-local halo exchange (R7/R8 lineage), zero barriers; lane
// owns 2 cols; 4-slot raw ring in regs; H ring 4-deep; rsq epilogue; EDGEY.
//
// Cross-round bottleneck isolation (R2/R8/R9): per-step wall-cycles --
// R2 (no shuffles, fat loads): 1.88k | R8 (12 shuffles, 4 w/SIMD): 3.36k |
// R9 (12 shuffles, 2-step prefetch, 2 w/SIMD): 3.2k. Deeper prefetch and
// wave count DON'T move it -> stall is the two dependent __shfl rounds:
// hipcc lowers them to ds_bpermute (LDS pipe, ~120cy + queueing behind
// 16 waves x 12 ops, x2 sequential rounds = the ~1.4k delta).
// R9 also: 20-phase unroll blew VGPR to 120 (codegen hoisting) -> stick
// with R8's 4-phase body.
//
// R10: ONE lever -- distance-1 shuffles become DPP whole-wave shifts
// (v_mov_b32_dpp wave_shl:1 / wave_shr:1), which execute on the VALU pipe:
// ~2cy issue, ALU-latency dependence, zero LDS. bound_ctrl=1 zero-fills
// lane 0/63; safe because the contaminated values (lane0 col-0 chain,
// lane63 vR/cR) only feed ownf=0 outputs and are never read by neighbors
// (lane1's halo product needs lane0's c1_1, whose mu uses no left halo).
// Everything else is R8 byte-identical (RY=37, grid (9,111)=999 blocks,
// single-round at 4 waves/SIMD; VGPR 60).

#define HH 4096
#define WW 4096
constexpr int RY   = 37;             // output rows per tile (37*111 = 4107 >= 4096)
constexpr int NYB  = 111;            // y tiles
constexpr int WOWN = 120;            // owned cols per wave
constexpr int WPB  = 4;              // waves per block
constexpr int NXB  = 9;              // x blocks (9*4*120 = 4320 >= 4096)
constexpr float EPf = 1e-20f;

// DPP whole-wave shifts (gfx9-lineage; VALU pipe, not LDS).
// wave_shl:1 = 0x130: lane i <- lane i-1  (== shfl_up 1);  lane 0 <- 0.
// wave_shr:1 = 0x138: lane i <- lane i+1  (== shfl_down 1); lane 63 <- 0.
__device__ __forceinline__ float up1(float v) {
    return __int_as_float(__builtin_amdgcn_update_dpp(
        0, __float_as_int(v), 0x130, 0xF, 0xF, true));
}
__device__ __forceinline__ float dn1(float v) {
    return __int_as_float(__builtin_amdgcn_update_dpp(
        0, __float_as_int(v), 0x138, 0xF, 0xF, true));
}

struct Regs {
    float ra[4][2], rb[4][2];               // raw ring: 4 rows x 2 cols x 2 imgs
    float Hii[4][2], Hjj[4][2], Hij[4][2];  // H ring per c-row
    float mc;                               // col-pair validity (image pad)
    float ownf;                             // ownership mask for emit
    float acc;
};

template <int SLOT, bool EDGEY>
__device__ __forceinline__ void ld_row(Regs& R,
        const float* __restrict__ i1, const float* __restrict__ i2,
        int t, int p0) {
    bool ok = ((unsigned)p0 < (unsigned)WW);
    if (EDGEY) ok = ok && ((unsigned)t < (unsigned)HH);
    float2 va = make_float2(0.f, 0.f), vb = make_float2(0.f, 0.f);
    if (ok) {
        const size_t off = (size_t)t * WW + (unsigned)p0;
        va = *(const float2*)(i1 + off);
        vb = *(const float2*)(i2 + off);
    }
    R.ra[SLOT][0] = va.x; R.ra[SLOT][1] = va.y;
    R.rb[SLOT][0] = vb.x; R.rb[SLOT][1] = vb.y;
}

// Step rr (c-row r = y0-1+rr), K = rr & 3. Row u lives in slot (u-y0)&3.
template <int K, bool EDGEY, bool DOLOAD>
__device__ __forceinline__ void step(Regs& R, int rr, int y0, int p0,
        const float* __restrict__ i1, const float* __restrict__ i2) {
    constexpr int Sm1 = (K + 2) & 3;   // row r-1 (freed by vs; load target r+3)
    constexpr int S0  = (K + 3) & 3;   // row r (center)
    constexpr int Sp1 =  K;            // row r+1
    constexpr int Sp2 = (K + 1) & 3;   // row r+2
    const int r = y0 - 1 + rr;

    // vertical 4-sums at own 2 cols (consumes oldest slot)
    const float vs1_0 = (R.ra[Sm1][0] + R.ra[S0][0]) + (R.ra[Sp1][0] + R.ra[Sp2][0]);
    const float vs1_1 = (R.ra[Sm1][1] + R.ra[S0][1]) + (R.ra[Sp1][1] + R.ra[Sp2][1]);
    const float vs2_0 = (R.rb[Sm1][0] + R.rb[S0][0]) + (R.rb[Sp1][0] + R.rb[Sp2][0]);
    const float vs2_1 = (R.rb[Sm1][1] + R.rb[S0][1]) + (R.rb[Sp1][1] + R.rb[Sp2][1]);

    // halo exchange round 1 (DPP): vs at cols p0-1 and p0+2, p0+3
    const float vL1  = up1(vs1_1), vL2  = up1(vs2_1);
    const float vR10 = dn1(vs1_0), vR11 = dn1(vs1_1);
    const float vR20 = dn1(vs2_0), vR21 = dn1(vs2_1);

    // prefetch row r+3 into freed slot; first consumed next step's vs
    if (DOLOAD)
        ld_row<Sm1, EDGEY>(R, i1, i2, y0 + 2 + rr, p0);

    // mu over cols [c-1, c+2]
    const float mu1_0 = ((vL1 + vs1_0) + (vs1_1 + vR10)) * 0.0625f;
    const float mu1_1 = ((vs1_0 + vs1_1) + (vR10 + vR11)) * 0.0625f;
    const float mu2_0 = ((vL2 + vs2_0) + (vs2_1 + vR20)) * 0.0625f;
    const float mu2_1 = ((vs2_0 + vs2_1) + (vR20 + vR21)) * 0.0625f;

    float msk = R.mc;
    if (EDGEY) msk *= (((unsigned)r < (unsigned)HH) ? 1.f : 0.f);

    const float c1_0 = (R.ra[S0][0] - mu1_0) * msk;
    const float c1_1 = (R.ra[S0][1] - mu1_1) * msk;
    const float c2_0 = (R.rb[S0][0] - mu2_0) * msk;
    const float c2_1 = (R.rb[S0][1] - mu2_1) * msk;

    // halo exchange round 2 (DPP): centered values at cols p0-1, p0+2, p0+3
    const float cL1  = up1(c1_1), cL2  = up1(c2_1);
    const float cR10 = dn1(c1_0), cR11 = dn1(c1_1);
    const float cR20 = dn1(c2_0), cR21 = dn1(c2_1);

    // products (own + halo, computed locally)
    const float pii0 = c1_0 * c1_0, pjj0 = c2_0 * c2_0, pij0 = c1_0 * c2_0;
    const float pii1 = c1_1 * c1_1, pjj1 = c2_1 * c2_1, pij1 = c1_1 * c2_1;
    const float pLii = cL1 * cL1,  pLjj = cL2 * cL2,  pLij = cL1 * cL2;
    const float pR0ii = cR10 * cR10, pR0jj = cR20 * cR20, pR0ij = cR10 * cR20;
    const float pR1ii = cR11 * cR11, pR1jj = cR21 * cR21, pR1ij = cR11 * cR21;

    // horizontal 4-sums over cols [o-1, o+2] -> H ring slot K
    {
        const float s = pii0 + pii1;
        R.Hii[K][0] = (pLii + s) + pR0ii;
        R.Hii[K][1] = (s + pR0ii) + pR1ii;
    }
    {
        const float s = pjj0 + pjj1;
        R.Hjj[K][0] = (pLjj + s) + pR0jj;
        R.Hjj[K][1] = (s + pR0jj) + pR1jj;
    }
    {
        const float s = pij0 + pij1;
        R.Hij[K][0] = (pLij + s) + pR0ij;
        R.Hij[K][1] = (s + pR0ij) + pR1ij;
    }

    // emit output row i = r-2 once H ring holds c-rows i-1..i+2.
    // EDGEY bottom-overhang tiles: skip rows i >= HH (wave-uniform guard).
    if (rr >= 3 && (!EDGEY || (r - 2 < HH))) {
#pragma unroll
        for (int q = 0; q < 2; ++q) {
            float sii = (R.Hii[0][q] + R.Hii[1][q]) + (R.Hii[2][q] + R.Hii[3][q]);
            float sjj = (R.Hjj[0][q] + R.Hjj[1][q]) + (R.Hjj[2][q] + R.Hjj[3][q]);
            float sij = (R.Hij[0][q] + R.Hij[1][q]) + (R.Hij[2][q] + R.Hij[3][q]);
            sii = fmaxf(sii, EPf);
            sjj = fmaxf(sjj, EPf);
            const float pr = fmaxf(sii * sjj, 1e-35f);  // denormal-flush guard
            float L = sij * __builtin_amdgcn_rsqf(pr);
            L = fmaxf(L, -1.f);
            R.acc += R.ownf * (1.f - L);
        }
    }
}

template <bool EDGEY>
__device__ float run_tile(const float* __restrict__ i1, const float* __restrict__ i2,
                          int y0, int p0, float mc, float ownf) {
    Regs R;
    R.mc = mc; R.ownf = ownf; R.acc = 0.f;

    // prime ring: rows y0-2..y0+1 -> slots 2,3,0,1  (slot = (row-y0)&3)
    ld_row<2, EDGEY>(R, i1, i2, y0 - 2, p0);
    ld_row<3, EDGEY>(R, i1, i2, y0 - 1, p0);
    ld_row<0, EDGEY>(R, i1, i2, y0,     p0);
    ld_row<1, EDGEY>(R, i1, i2, y0 + 1, p0);

    // steps rr = 0..RY+2 = 0..39 (40 = 10x4); step rr loads row y0+2+rr,
    // needed through row y0+RY+3 -> last load at rr = RY+1 = 38.
#pragma unroll 1
    for (int o = 0; o < 9; ++o) {
        const int rrb = o * 4;
        step<0, EDGEY, true>(R, rrb + 0, y0, p0, i1, i2);
        step<1, EDGEY, true>(R, rrb + 1, y0, p0, i1, i2);
        step<2, EDGEY, true>(R, rrb + 2, y0, p0, i1, i2);
        step<3, EDGEY, true>(R, rrb + 3, y0, p0, i1, i2);
    }
    step<0, EDGEY, true >(R, 36, y0, p0, i1, i2);
    step<1, EDGEY, true >(R, 37, y0, p0, i1, i2);
    step<2, EDGEY, true >(R, 38, y0, p0, i1, i2);
    step<3, EDGEY, false>(R, 39, y0, p0, i1, i2);

    return R.acc;
}

__global__ __launch_bounds__(256) void xcorr_loss_kernel(
        const float* __restrict__ img1, const float* __restrict__ img2,
        double* __restrict__ ws) {
    const int tid  = threadIdx.x;
    const int lane = tid & 63;
    const int wv   = tid >> 6;
    const int WX0  = (blockIdx.x * WPB + wv) * WOWN;
    const int p0   = WX0 - 4 + 2 * lane;        // own cols p0, p0+1 (p0 even)
    const int y0   = blockIdx.y * RY;

    const float mc   = ((unsigned)p0 < (unsigned)WW) ? 1.f : 0.f;
    const float ownf = (lane >= 2 && lane <= 61 && (unsigned)p0 < (unsigned)WW)
                       ? 1.f : 0.f;

    float acc;
    if (blockIdx.y == 0 || blockIdx.y == gridDim.y - 1)
        acc = run_tile<true >(img1, img2, y0, p0, mc, ownf);
    else
        acc = run_tile<false>(img1, img2, y0, p0, mc, ownf);

    // wave reduction -> LDS -> one double atomic per block
    float wsum = acc;
#pragma unroll
    for (int off = 32; off > 0; off >>= 1)
        wsum += __shfl_down(wsum, off, 64);

    __shared__ float wpart[WPB];
    if (lane == 0) wpart[wv] = wsum;
    __syncthreads();
    if (tid == 0)
        atomicAdd(ws, (double)((wpart[0] + wpart[1]) + (wpart[2] + wpart[3])));
}

__global__ void finalize_kernel(const double* __restrict__ ws, float* __restrict__ out) {
    double mean = ws[0] / ((double)HH * (double)WW);
    out[0] = (float)mean;
    out[1] = (float)mean;
}

extern "C" void kernel_launch(void* const* d_in, const int* in_sizes, int n_in,
                              void* d_out, int out_size, void* d_ws, size_t ws_size,
                              hipStream_t stream) {
    const float* img1 = (const float*)d_in[0];  // outputs
    const float* img2 = (const float*)d_in[1];  // labels
    double* ws = (double*)d_ws;

    hipMemsetAsync(d_ws, 0, sizeof(double), stream);

    dim3 grid(NXB, NYB);   // (9, 111) = 999 blocks, single round at 4 w/SIMD
    xcorr_loss_kernel<<<grid, dim3(256), 0, stream>>>(img1, img2, ws);
    finalize_kernel<<<1, 1, 0, stream>>>(ws, (float*)d_out);
}